// Round 27
// baseline (111.820 us; speedup 1.0000x reference)
//
#include <hip/hip_runtime.h>

#define B_  2
#define S_  2048
#define H_  1024
#define NH_ 16
#define HD_ 64
#define M_  (B_ * S_)   // 4096

typedef short  short8  __attribute__((ext_vector_type(8)));
typedef __bf16 bf16x8  __attribute__((ext_vector_type(8)));
typedef float  f32x4   __attribute__((ext_vector_type(4)));

__device__ __forceinline__ ushort f2bf(float f) {
  union { float f; unsigned u; } v; v.f = f;
  unsigned r = v.u + 0x7fffu + ((v.u >> 16) & 1u);   // RNE
  return (ushort)(r >> 16);
}
__device__ __forceinline__ float bf2f(ushort u) {
  union { unsigned u; float f; } v; v.u = ((unsigned)u) << 16;
  return v.f;
}
// packed bf16 pair via HW cvt (RNE): dst.lo=bf16(lo), dst.hi=bf16(hi)
__device__ __forceinline__ unsigned cvtpk(float lo, float hi) {
  unsigned r;
  asm("v_cvt_pk_bf16_f32 %0, %1, %2" : "=v"(r) : "v"(lo), "v"(hi));
  return r;
}

__device__ __forceinline__ void gload_lds16(const void* g, void* l) {
  __builtin_amdgcn_global_load_lds(
      (const __attribute__((address_space(1))) void*)g,
      (__attribute__((address_space(3))) void*)l, 16, 0, 0);
}

__device__ __forceinline__ f32x4 mfma_bf16(short8 a, short8 b, f32x4 c) {
  return __builtin_amdgcn_mfma_f32_16x16x32_bf16(
      __builtin_bit_cast(bf16x8, a), __builtin_bit_cast(bf16x8, b), c, 0, 0, 0);
}

// swizzled element offsets; c = 16B chunk index
__device__ __forceinline__ int swzK(int r, int c) {   // [R][64] tiles
  return r * 64 + ((c ^ (r & 7)) << 3);
}
__device__ __forceinline__ int swzV(int r, int c) {   // [R][128] tiles
  return r * 128 + ((c ^ (r & 7)) << 3);
}

// reduce over lanes {l, l^16, l^32, l^48} — known-good shfl_xor pair
__device__ __forceinline__ float redmax64(float a) {
  a = fmaxf(a, __shfl_xor(a, 16));
  a = fmaxf(a, __shfl_xor(a, 32));
  return a;
}

// ---------------------------------------------------------------- prep (fused)
// blocks [0,4096): x f32->bf16; [4096,8192): W q/k/v/o; [8192,8448): rope tables
__global__ __launch_bounds__(256)
void prep(const float* __restrict__ x, const float* __restrict__ Wq,
          const float* __restrict__ Wk, const float* __restrict__ Wv,
          const float* __restrict__ Wo, ushort* __restrict__ xb,
          ushort* __restrict__ Wqkv, ushort* __restrict__ Wob,
          float* __restrict__ ct, float* __restrict__ st) {
  int bid = blockIdx.x, t = threadIdx.x;
  if (bid < 4096) {
    int i = (bid * 256 + t) * 4;
    float4 v = *(const float4*)&x[i];
    ushort4 o;
    o.x = f2bf(v.x); o.y = f2bf(v.y); o.z = f2bf(v.z); o.w = f2bf(v.w);
    *(ushort4*)&xb[i] = o;
  } else if (bid < 8192) {
    int y = (bid - 4096) >> 10;
    const float* src = (y == 0) ? Wq : (y == 1) ? Wk : (y == 2) ? Wv : Wo;
    ushort* dst = (y == 3) ? Wob : Wqkv + (size_t)y * H_ * H_;
    int i = (((bid - 4096) & 1023) * 256 + t) * 4;
    float4 v = *(const float4*)&src[i];
    ushort4 o;
    o.x = f2bf(v.x); o.y = f2bf(v.y); o.z = f2bf(v.z); o.w = f2bf(v.w);
    *(ushort4*)&dst[i] = o;
  } else {
    int i = (bid - 8192) * 256 + t;     // < S_*32
    int pos = i >> 5, d2 = i & 31;
    float invf = powf(10000.0f, -(float)d2 / 32.0f);
    float fr = (float)pos * invf;
    ct[i] = cosf(fr);
    st[i] = sinf(fr);
  }
}

// ---------------------------------------------------------------- QKV GEMM (fused epilogue)
// BK=32, TRIPLE-buffered (48 KB), counted vmcnt(4) + raw s_barrier per iter.
__global__ __launch_bounds__(256)
void gemm_qkv(const ushort* __restrict__ A, const ushort* __restrict__ Bm,
              int Kdim, const float* __restrict__ ct, const float* __restrict__ st,
              ushort* __restrict__ qb, ushort* __restrict__ kb,
              ushort* __restrict__ vt) {
  __shared__ ushort SMEM[6 * 4096];    // 48 KB: A bufs [0..3), B bufs [3..6)
  int t = threadIdx.x;
  int w = t >> 6, l = t & 63;
  int nbx = (int)gridDim.x;
  int nwg = nbx * (int)gridDim.y;
  int bid = (int)blockIdx.x + nbx * (int)blockIdx.y;
  int cpx = nwg >> 3;                          // nwg % 8 == 0
  int sbid = (bid & 7) * cpx + (bid >> 3);
  int m0 = (sbid / nbx) * 128, n0 = (sbid % nbx) * 128;
  int wr = (w >> 1) * 64, wc = (w & 1) * 64;
  int lrow = l & 15, g = l >> 4, lk8 = g * 8;
  int arow = t >> 2, acol = (t & 3) * 8;

  f32x4 acc[4][4];
#pragma unroll
  for (int mi = 0; mi < 4; ++mi)
#pragma unroll
    for (int ni = 0; ni < 4; ++ni) acc[mi][ni] = f32x4{0.f, 0.f, 0.f, 0.f};

  int nk = Kdim >> 5;
#pragma unroll
  for (int pt = 0; pt < 2; ++pt) {
    int k0 = pt << 5;
    ushort* An = SMEM + pt * 4096;
    ushort* Bn = SMEM + 12288 + pt * 4096;
#pragma unroll
    for (int c = 0; c < 2; ++c) {
      gload_lds16(&A[(size_t)(m0 + arow + c * 64) * Kdim + k0 + acol],
                  &An[(c * 256 + w * 64) * 8]);
      gload_lds16(&Bm[(size_t)(n0 + arow + c * 64) * Kdim + k0 + acol],
                  &Bn[(c * 256 + w * 64) * 8]);
    }
  }

  int cur = 0;
  for (int ki = 0; ki < nk; ++ki) {
    if (ki < nk - 1)
      asm volatile("s_waitcnt vmcnt(4)" ::: "memory");
    else
      asm volatile("s_waitcnt vmcnt(0)" ::: "memory");
    __builtin_amdgcn_s_barrier();

    if (ki + 2 < nk) {
      int tb = cur + 2; if (tb >= 3) tb -= 3;
      int k0 = (ki + 2) << 5;
      ushort* An = SMEM + tb * 4096;
      ushort* Bn = SMEM + 12288 + tb * 4096;
#pragma unroll
      for (int c = 0; c < 2; ++c) {
        gload_lds16(&A[(size_t)(m0 + arow + c * 64) * Kdim + k0 + acol],
                    &An[(c * 256 + w * 64) * 8]);
        gload_lds16(&Bm[(size_t)(n0 + arow + c * 64) * Kdim + k0 + acol],
                    &Bn[(c * 256 + w * 64) * 8]);
      }
    }

    const ushort* Ac = SMEM + cur * 4096;
    const ushort* Bc = SMEM + 12288 + cur * 4096;
    short8 af[4], bfr[4];
#pragma unroll
    for (int i = 0; i < 4; ++i)
      af[i] = *(const short8*)&Ac[(wr + i * 16 + lrow) * 32 + lk8];
#pragma unroll
    for (int i = 0; i < 4; ++i)
      bfr[i] = *(const short8*)&Bc[(wc + i * 16 + lrow) * 32 + lk8];
#pragma unroll
    for (int mi = 0; mi < 4; ++mi)
#pragma unroll
      for (int ni = 0; ni < 4; ++ni)
        acc[mi][ni] = mfma_bf16(af[mi], bfr[ni], acc[mi][ni]);

    ++cur; if (cur == 3) cur = 0;
  }

  // fused epilogue: wave's 64 cols = one head; sector is BLOCK-uniform
  int colbase = n0 + wc;
  int sector = n0 >> 10;               // 0=q, 1=k, 2=v
  int h = (colbase & 1023) >> 6;
  if (sector < 2) {
    ushort* dst = (sector == 0) ? qb : kb;
    const float SCq = (sector == 0) ? 0.125f * 1.44269504f : 1.0f;
#pragma unroll
    for (int mi = 0; mi < 4; ++mi)
#pragma unroll
      for (int j = 0; j < 4; ++j) {
        int row = m0 + wr + mi * 16 + g * 4 + j;
        int b = row >> 11, s = row & 2047;
        size_t o = ((size_t)(b * NH_ + h) * S_ + s) * HD_;
        float c0 = ct[s * 32 + lrow],      s0 = st[s * 32 + lrow];
        float c1 = ct[s * 32 + 16 + lrow], s1 = st[s * 32 + 16 + lrow];
        float x1a = acc[mi][0][j], x2a = acc[mi][2][j];   // d = lrow, +32
        float x1b = acc[mi][1][j], x2b = acc[mi][3][j];   // d = 16+lrow, +48
        dst[o + lrow]      = f2bf((x1a * c0 - x2a * s0) * SCq);
        dst[o + lrow + 32] = f2bf((x2a * c0 + x1a * s0) * SCq);
        dst[o + lrow + 16] = f2bf((x1b * c1 - x2b * s1) * SCq);
        dst[o + lrow + 48] = f2bf((x2b * c1 + x1b * s1) * SCq);
      }
  } else {
    // V: stage [col][s] (swizzled) in SMEM[0..32KB), then coalesced
    // 64B stores along s. Block-uniform barriers.
    __syncthreads();
#pragma unroll
    for (int mi = 0; mi < 4; ++mi) {
      int s_local = wr + mi * 16 + g * 4;
#pragma unroll
      for (int ni = 0; ni < 4; ++ni) {
        int cl = wc + ni * 16 + lrow;
        uint2 pk;
        pk.x = cvtpk(acc[mi][ni][0], acc[mi][ni][1]);
        pk.y = cvtpk(acc[mi][ni][2], acc[mi][ni][3]);
        int a = cl * 128 + (((s_local >> 3) ^ (cl & 7)) << 3) + (s_local & 7);
        *(uint2*)&SMEM[a] = pk;
      }
    }
    __syncthreads();
    int b = m0 >> 11, s_base = m0 & 2047;
#pragma unroll
    for (int cc = 0; cc < 2; ++cc) {
      int u = cc * 256 + t;            // 512 units: 128 cols x 4 s-chunks
      int cl = u >> 2;
      int sq = (u & 3) * 32;
      int hh = ((n0 + cl) & 1023) >> 6;
      int d  = cl & 63;
      size_t ob = ((size_t)(b * NH_ + hh) * HD_ + d) * S_ + s_base + sq;
#pragma unroll
      for (int i = 0; i < 4; ++i) {
        int sl = sq + i * 8;
        int a = cl * 128 + (((sl >> 3) ^ (cl & 7)) << 3);
        *(short8*)&vt[ob + i * 8] = *(const short8*)&SMEM[a];
      }
    }
  }
}

// ---------------------------------------------------------------- out GEMM
// 32x128 tiles -> 1024 blocks = 4 blocks/CU TLP. BK=32, triple-buffered
// (30 KB), counted vmcnt(2) (waves 0-1: 3 loads/batch, waves 2-3: 2). C f32.
__global__ __launch_bounds__(256)
void gemm_out(const ushort* __restrict__ A, const ushort* __restrict__ Bm,
              float* __restrict__ Cout, int Ndim, int Kdim) {
  __shared__ ushort SMEM[3 * 1024 + 3 * 4096];   // A bufs 3x2KB, B bufs 3x8KB
  ushort* ABUF = SMEM;                           // [3][32*32]
  ushort* BBUF = SMEM + 3 * 1024;                // [3][128*32]
  int t = threadIdx.x;
  int w = t >> 6, l = t & 63;
  int nbx = (int)gridDim.x;                      // 8 (n tiles of 128)
  int nwg = nbx * (int)gridDim.y;                // 1024
  int bid = (int)blockIdx.x + nbx * (int)blockIdx.y;
  int cpx = nwg >> 3;
  int sbid = (bid & 7) * cpx + (bid >> 3);
  int m0 = (sbid / nbx) * 32, n0 = (sbid % nbx) * 128;
  int wc = w * 32;                               // each wave: 32 output cols
  int lrow = l & 15, g = l >> 4, lk8 = g * 8;
  int arow = t >> 2, acol = (t & 3) * 8;   // B staging: 64 rows x 4 chunks (+64)

  f32x4 acc[2][2];
#pragma unroll
  for (int mi = 0; mi < 2; ++mi)
#pragma unroll
    for (int ni = 0; ni < 2; ++ni) acc[mi][ni] = f32x4{0.f, 0.f, 0.f, 0.f};

  int nk = Kdim >> 5;
#pragma unroll
  for (int pt = 0; pt < 2; ++pt) {
    int k0 = pt << 5;
    ushort* An = ABUF + pt * 1024;
    ushort* Bn = BBUF + pt * 4096;
    if (t < 128)   // waves 0-1: A tile 32x32 = 128 x 16B loads
      gload_lds16(&A[(size_t)(m0 + (t >> 2)) * Kdim + k0 + (t & 3) * 8],
                  &An[t * 8]);
#pragma unroll
    for (int c = 0; c < 2; ++c)
      gload_lds16(&Bm[(size_t)(n0 + arow + c * 64) * Kdim + k0 + acol],
                  &Bn[(c * 256 + w * 64) * 8]);
  }

  int cur = 0;
  for (int ki = 0; ki < nk; ++ki) {
    if (ki < nk - 1)
      asm volatile("s_waitcnt vmcnt(2)" ::: "memory");
    else
      asm volatile("s_waitcnt vmcnt(0)" ::: "memory");
    __builtin_amdgcn_s_barrier();

    if (ki + 2 < nk) {
      int tb = cur + 2; if (tb >= 3) tb -= 3;
      int k0 = (ki + 2) << 5;
      ushort* An = ABUF + tb * 1024;
      ushort* Bn = BBUF + tb * 4096;
      if (t < 128)
        gload_lds16(&A[(size_t)(m0 + (t >> 2)) * Kdim + k0 + (t & 3) * 8],
                    &An[t * 8]);
#pragma unroll
      for (int c = 0; c < 2; ++c)
        gload_lds16(&Bm[(size_t)(n0 + arow + c * 64) * Kdim + k0 + acol],
                    &Bn[(c * 256 + w * 64) * 8]);
    }

    const ushort* Ac = ABUF + cur * 1024;
    const ushort* Bc = BBUF + cur * 4096;
    short8 af[2], bfr[2];
#pragma unroll
    for (int i = 0; i < 2; ++i)
      af[i] = *(const short8*)&Ac[(i * 16 + lrow) * 32 + lk8];
#pragma unroll
    for (int i = 0; i < 2; ++i)
      bfr[i] = *(const short8*)&Bc[(wc + i * 16 + lrow) * 32 + lk8];
#pragma unroll
    for (int mi = 0; mi < 2; ++mi)
#pragma unroll
      for (int ni = 0; ni < 2; ++ni)
        acc[mi][ni] = mfma_bf16(af[mi], bfr[ni], acc[mi][ni]);

    ++cur; if (cur == 3) cur = 0;
  }

#pragma unroll
  for (int mi = 0; mi < 2; ++mi)
#pragma unroll
    for (int ni = 0; ni < 2; ++ni)
#pragma unroll
      for (int j = 0; j < 4; ++j) {
        int row = m0 + mi * 16 + g * 4 + j;
        int col = n0 + wc + ni * 16 + lrow;
        Cout[(size_t)row * Ndim + col] = acc[mi][ni][j];
      }
}

// ---------------------------------------------------------------- flash attention v10
// (best measured: 45.3 µs) 64 KB LDS; Q direct-to-reg; K single-buffered
// (staged post-QK-barrier, hidden under softmax+PV); V double-buffered.
__global__ __launch_bounds__(512, 4)
void flash_attn(const ushort* __restrict__ qb, const ushort* __restrict__ kb,
                const ushort* __restrict__ vt, ushort* __restrict__ ctx) {
  __shared__ ushort Ks[128 * 64];      // [key][d] swizzled, single buffer
  __shared__ ushort Vs[2][64 * 128];   // [d][key] swizzled, double buffer
  __shared__ ushort Ps[128 * 64];      // P (swizzled), wave-private rows
  int bh = blockIdx.y;
  int qt = (blockIdx.y & 16) ? (int)blockIdx.x : (15 - (int)blockIdx.x);
  int b = bh >> 4, h = bh & 15;
  int t = threadIdx.x, w = t >> 6, l = t & 63;
  int lrow = l & 15, g = l >> 4;
  int wrow = w * 16;
  const ushort* Q = qb + (size_t)bh * S_ * HD_;
  const ushort* K = kb + (size_t)bh * S_ * HD_;
  const ushort* V = vt + (size_t)bh * HD_ * S_;   // [64][2048]

  short8 ones;
#pragma unroll
  for (int i = 0; i < 8; ++i) ones[i] = (short)0x3F80;   // bf16 1.0

  // prologue: K/V tile 0 -> LDS; Q -> registers
#pragma unroll
  for (int cc = 0; cc < 2; ++cc) {
    int slot = cc * 512 + t;
    int r = slot >> 3, c = slot & 7;
    int cs = (c ^ (r & 7)) << 3;
    gload_lds16(&K[(size_t)r * 64 + cs], &Ks[slot * 8]);
  }
#pragma unroll
  for (int cc = 0; cc < 2; ++cc) {
    int slot = cc * 512 + t;
    int r = slot >> 4, c = slot & 15;
    int cs = (c ^ (r & 7)) << 3;
    gload_lds16(&V[(size_t)r * S_ + cs], &Vs[0][slot * 8]);
  }
  short8 aq[2];
  {
    int qrow = qt * 128 + wrow + lrow;
#pragma unroll
    for (int ks = 0; ks < 2; ++ks)
      aq[ks] = *(const short8*)&Q[(size_t)qrow * 64 + ks * 32 + g * 8];
  }
  __syncthreads();

  float m_ = -1e30f, ls_ = 0.f;
  f32x4 O[4];
#pragma unroll
  for (int nf = 0; nf < 4; ++nf) O[nf] = f32x4{0.f, 0.f, 0.f, 0.f};

  int nkt = qt + 1;
  for (int kt = 0; kt < nkt; ++kt) {
    const ushort* Vc = Vs[kt & 1];

    // S^T = K Q^T : lane q = wrow+lrow; key = nf*16 + g*4 + j
    f32x4 sc[8];
#pragma unroll
    for (int nf = 0; nf < 8; ++nf) sc[nf] = f32x4{0.f, 0.f, 0.f, 0.f};
    __builtin_amdgcn_s_setprio(1);
#pragma unroll
    for (int ks = 0; ks < 2; ++ks)
#pragma unroll
      for (int nf = 0; nf < 8; ++nf) {
        short8 bk = *(const short8*)&Ks[swzK(nf * 16 + lrow, ks * 4 + g)];
        sc[nf] = mfma_bf16(bk, aq[ks], sc[nf]);
      }
    __builtin_amdgcn_s_setprio(0);

    __syncthreads();   // all waves done reading Ks; nothing else in flight

    // stage K/V for kt+1 (async; lands during softmax+PV below)
    if (kt + 1 < nkt) {
      int nb = (kt + 1) & 1;
#pragma unroll
      for (int cc = 0; cc < 2; ++cc) {
        int slot = cc * 512 + t;
        int r = slot >> 3, c = slot & 7;
        int cs = (c ^ (r & 7)) << 3;
        gload_lds16(&K[(size_t)((kt + 1) * 128 + r) * 64 + cs], &Ks[slot * 8]);
      }
#pragma unroll
      for (int cc = 0; cc < 2; ++cc) {
        int slot = cc * 512 + t;
        int r = slot >> 4, c = slot & 15;
        int cs = (c ^ (r & 7)) << 3;
        gload_lds16(&V[(size_t)r * S_ + (kt + 1) * 128 + cs], &Vs[nb][slot * 8]);
      }
    }

    int qbase = qt * 128 + wrow;
    if (kt * 128 + 127 > qbase) {   // wave-uniform; only the diagonal tile
      int qi = qbase + lrow;
#pragma unroll
      for (int nf = 0; nf < 8; ++nf) {
        int kbase = kt * 128 + nf * 16 + g * 4;
#pragma unroll
        for (int j = 0; j < 4; ++j)
          if (kbase + j > qi) sc[nf][j] = -1e30f;
      }
    }

    // row max: pairwise tree + 2 shuffles
    f32x4 v4 = sc[0];
#pragma unroll
    for (int nf = 1; nf < 8; ++nf)
#pragma unroll
      for (int j = 0; j < 4; ++j) v4[j] = fmaxf(v4[j], sc[nf][j]);
    float mx = redmax64(fmaxf(fmaxf(v4[0], v4[1]), fmaxf(v4[2], v4[3])));

    // defer-max (T13)
    bool nor = __all(mx <= m_ + 8.f);
    if (!nor) {
      float mnew = fmaxf(m_, mx);
      float al = exp2f(m_ - mnew);
      m_ = mnew;
      ls_ *= al;
#pragma unroll
      for (int nf = 0; nf < 4; ++nf)
#pragma unroll
        for (int j = 0; j < 4; ++j) O[nf][j] *= al;
    }

    // exp2 (row sum comes from the ones-MFMA below)
#pragma unroll
    for (int nf = 0; nf < 8; ++nf)
#pragma unroll
      for (int j = 0; j < 4; ++j) sc[nf][j] = exp2f(sc[nf][j] - m_);

    // PV in two 64-key halves through the wave-private P rows;
    // sacc accumulates the bf16-P row sum via mfma(ones, ap).
    f32x4 sacc = f32x4{0.f, 0.f, 0.f, 0.f};
#pragma unroll
    for (int half = 0; half < 2; ++half) {
      int prow = wrow + lrow;
#pragma unroll
      for (int nf2 = 0; nf2 < 4; ++nf2) {
        int nf = half * 4 + nf2;
        uint2 pk;
        pk.x = cvtpk(sc[nf][0], sc[nf][1]);
        pk.y = cvtpk(sc[nf][2], sc[nf][3]);
        *(uint2*)&Ps[swzK(prow, nf2 * 2 + (g >> 1)) + (g & 1) * 4] = pk;
      }
      __builtin_amdgcn_s_setprio(1);
#pragma unroll
      for (int ks2 = 0; ks2 < 2; ++ks2) {
        short8 ap = *(const short8*)&Ps[swzK(wrow + lrow, ks2 * 4 + g)];
        sacc = mfma_bf16(ones, ap, sacc);   // row sum, replicated in all regs
#pragma unroll
        for (int nf = 0; nf < 4; ++nf) {
          short8 bv = *(const short8*)&Vc[swzV(nf * 16 + lrow, half * 8 + ks2 * 4 + g)];
          O[nf] = mfma_bf16(bv, ap, O[nf]);
        }
      }
      __builtin_amdgcn_s_setprio(0);
    }
    ls_ += sacc[0];

    __syncthreads();   // staging drained; K/V ready for kt+1
  }

  // epilogue: lane q = wrow+lrow, d = nf*16 + g*4 + j
  float inv = 1.f / ls_;
  int srow = qt * 128 + wrow + lrow;
#pragma unroll
  for (int nf = 0; nf < 4; ++nf) {
    uint2 pk;
    pk.x = cvtpk(O[nf][0] * inv, O[nf][1] * inv);
    pk.y = cvtpk(O[nf][2] * inv, O[nf][3] * inv);
    *(uint2*)&ctx[((size_t)b * S_ + srow) * H_ + h * 64 + nf * 16 + g * 4] = pk;
  }
}

// ---------------------------------------------------------------- launch
extern "C" void kernel_launch(void* const* d_in, const int* in_sizes, int n_in,
                              void* d_out, int out_size, void* d_ws, size_t ws_size,
                              hipStream_t stream) {
  const float* x  = (const float*)d_in[0];
  const float* Wq = (const float*)d_in[1];
  const float* Wk = (const float*)d_in[2];
  const float* Wv = (const float*)d_in[3];
  const float* Wo = (const float*)d_in[4];

  char* ws = (char*)d_ws;
  size_t off = 0;
  ushort* xb   = (ushort*)(ws + off); off += (size_t)M_ * H_ * 2;
  ushort* Wqkv = (ushort*)(ws + off); off += (size_t)3 * H_ * H_ * 2;
  ushort* Wob  = (ushort*)(ws + off); off += (size_t)H_ * H_ * 2;
  float*  ct   = (float*)(ws + off);  off += (size_t)S_ * 32 * 4;
  float*  st   = (float*)(ws + off);  off += (size_t)S_ * 32 * 4;
  ushort* qb   = (ushort*)(ws + off); off += (size_t)M_ * H_ * 2;
  ushort* kb   = (ushort*)(ws + off); off += (size_t)M_ * H_ * 2;
  ushort* vtb  = (ushort*)(ws + off); off += (size_t)M_ * H_ * 2;
  ushort* ctx  = (ushort*)(ws + off); off += (size_t)M_ * H_ * 2;

  prep<<<8448, 256, 0, stream>>>(x, Wq, Wk, Wv, Wo, xb, Wqkv, Wob, ct, st);

  gemm_qkv<<<dim3(3 * H_ / 128, M_ / 128), 256, 0, stream>>>(
      xb, Wqkv, H_, ct, st, qb, kb, vtb);
  flash_attn<<<dim3(S_ / 128, B_ * NH_), 512, 0, stream>>>(qb, kb, vtb, ctx);
  gemm_out<<<dim3(H_ / 128, M_ / 32), 256, 0, stream>>>(
      ctx, Wob, (float*)d_out, H_, H_);
}

// Round 28
// 107.211 us; speedup vs baseline: 1.0430x; 1.0430x over previous
//
#include <hip/hip_runtime.h>

#define B_  2
#define S_  2048
#define H_  1024
#define NH_ 16
#define HD_ 64
#define M_  (B_ * S_)   // 4096

typedef short  short8  __attribute__((ext_vector_type(8)));
typedef __bf16 bf16x8  __attribute__((ext_vector_type(8)));
typedef float  f32x4   __attribute__((ext_vector_type(4)));

__device__ __forceinline__ ushort f2bf(float f) {
  union { float f; unsigned u; } v; v.f = f;
  unsigned r = v.u + 0x7fffu + ((v.u >> 16) & 1u);   // RNE
  return (ushort)(r >> 16);
}
__device__ __forceinline__ float bf2f(ushort u) {
  union { unsigned u; float f; } v; v.u = ((unsigned)u) << 16;
  return v.f;
}
// packed bf16 pair via HW cvt (RNE): dst.lo=bf16(lo), dst.hi=bf16(hi)
__device__ __forceinline__ unsigned cvtpk(float lo, float hi) {
  unsigned r;
  asm("v_cvt_pk_bf16_f32 %0, %1, %2" : "=v"(r) : "v"(lo), "v"(hi));
  return r;
}

__device__ __forceinline__ void gload_lds16(const void* g, void* l) {
  __builtin_amdgcn_global_load_lds(
      (const __attribute__((address_space(1))) void*)g,
      (__attribute__((address_space(3))) void*)l, 16, 0, 0);
}

__device__ __forceinline__ f32x4 mfma_bf16(short8 a, short8 b, f32x4 c) {
  return __builtin_amdgcn_mfma_f32_16x16x32_bf16(
      __builtin_bit_cast(bf16x8, a), __builtin_bit_cast(bf16x8, b), c, 0, 0, 0);
}

// swizzled element offsets; c = 16B chunk index
__device__ __forceinline__ int swzK(int r, int c) {   // [R][64] tiles
  return r * 64 + ((c ^ (r & 7)) << 3);
}
__device__ __forceinline__ int swzV(int r, int c) {   // [R][128] tiles
  return r * 128 + ((c ^ (r & 7)) << 3);
}

// reduce over lanes {l, l^16, l^32, l^48} — known-good shfl_xor pair
__device__ __forceinline__ float redmax64(float a) {
  a = fmaxf(a, __shfl_xor(a, 16));
  a = fmaxf(a, __shfl_xor(a, 32));
  return a;
}

// ---------------------------------------------------------------- prep (fused)
// blocks [0,4096): x f32->bf16; [4096,8192): W q/k/v/o; [8192,8448): rope tables
__global__ __launch_bounds__(256)
void prep(const float* __restrict__ x, const float* __restrict__ Wq,
          const float* __restrict__ Wk, const float* __restrict__ Wv,
          const float* __restrict__ Wo, ushort* __restrict__ xb,
          ushort* __restrict__ Wqkv, ushort* __restrict__ Wob,
          float* __restrict__ ct, float* __restrict__ st) {
  int bid = blockIdx.x, t = threadIdx.x;
  if (bid < 4096) {
    int i = (bid * 256 + t) * 4;
    float4 v = *(const float4*)&x[i];
    ushort4 o;
    o.x = f2bf(v.x); o.y = f2bf(v.y); o.z = f2bf(v.z); o.w = f2bf(v.w);
    *(ushort4*)&xb[i] = o;
  } else if (bid < 8192) {
    int y = (bid - 4096) >> 10;
    const float* src = (y == 0) ? Wq : (y == 1) ? Wk : (y == 2) ? Wv : Wo;
    ushort* dst = (y == 3) ? Wob : Wqkv + (size_t)y * H_ * H_;
    int i = (((bid - 4096) & 1023) * 256 + t) * 4;
    float4 v = *(const float4*)&src[i];
    ushort4 o;
    o.x = f2bf(v.x); o.y = f2bf(v.y); o.z = f2bf(v.z); o.w = f2bf(v.w);
    *(ushort4*)&dst[i] = o;
  } else {
    int i = (bid - 8192) * 256 + t;     // < S_*32
    int pos = i >> 5, d2 = i & 31;
    float invf = powf(10000.0f, -(float)d2 / 32.0f);
    float fr = (float)pos * invf;
    ct[i] = cosf(fr);
    st[i] = sinf(fr);
  }
}

// ---------------------------------------------------------------- QKV GEMM (fused epilogue)
// BK=32, TRIPLE-buffered (48 KB), counted vmcnt(4) + raw s_barrier per iter.
__global__ __launch_bounds__(256)
void gemm_qkv(const ushort* __restrict__ A, const ushort* __restrict__ Bm,
              int Kdim, const float* __restrict__ ct, const float* __restrict__ st,
              ushort* __restrict__ qb, ushort* __restrict__ kb,
              ushort* __restrict__ vt) {
  __shared__ ushort SMEM[6 * 4096];    // 48 KB: A bufs [0..3), B bufs [3..6)
  int t = threadIdx.x;
  int w = t >> 6, l = t & 63;
  int nbx = (int)gridDim.x;
  int nwg = nbx * (int)gridDim.y;
  int bid = (int)blockIdx.x + nbx * (int)blockIdx.y;
  int cpx = nwg >> 3;                          // nwg % 8 == 0
  int sbid = (bid & 7) * cpx + (bid >> 3);
  int m0 = (sbid / nbx) * 128, n0 = (sbid % nbx) * 128;
  int wr = (w >> 1) * 64, wc = (w & 1) * 64;
  int lrow = l & 15, g = l >> 4, lk8 = g * 8;
  int arow = t >> 2, acol = (t & 3) * 8;

  f32x4 acc[4][4];
#pragma unroll
  for (int mi = 0; mi < 4; ++mi)
#pragma unroll
    for (int ni = 0; ni < 4; ++ni) acc[mi][ni] = f32x4{0.f, 0.f, 0.f, 0.f};

  int nk = Kdim >> 5;
#pragma unroll
  for (int pt = 0; pt < 2; ++pt) {
    int k0 = pt << 5;
    ushort* An = SMEM + pt * 4096;
    ushort* Bn = SMEM + 12288 + pt * 4096;
#pragma unroll
    for (int c = 0; c < 2; ++c) {
      gload_lds16(&A[(size_t)(m0 + arow + c * 64) * Kdim + k0 + acol],
                  &An[(c * 256 + w * 64) * 8]);
      gload_lds16(&Bm[(size_t)(n0 + arow + c * 64) * Kdim + k0 + acol],
                  &Bn[(c * 256 + w * 64) * 8]);
    }
  }

  int cur = 0;
  for (int ki = 0; ki < nk; ++ki) {
    if (ki < nk - 1)
      asm volatile("s_waitcnt vmcnt(4)" ::: "memory");
    else
      asm volatile("s_waitcnt vmcnt(0)" ::: "memory");
    __builtin_amdgcn_s_barrier();

    if (ki + 2 < nk) {
      int tb = cur + 2; if (tb >= 3) tb -= 3;
      int k0 = (ki + 2) << 5;
      ushort* An = SMEM + tb * 4096;
      ushort* Bn = SMEM + 12288 + tb * 4096;
#pragma unroll
      for (int c = 0; c < 2; ++c) {
        gload_lds16(&A[(size_t)(m0 + arow + c * 64) * Kdim + k0 + acol],
                    &An[(c * 256 + w * 64) * 8]);
        gload_lds16(&Bm[(size_t)(n0 + arow + c * 64) * Kdim + k0 + acol],
                    &Bn[(c * 256 + w * 64) * 8]);
      }
    }

    const ushort* Ac = SMEM + cur * 4096;
    const ushort* Bc = SMEM + 12288 + cur * 4096;
    short8 af[4], bfr[4];
#pragma unroll
    for (int i = 0; i < 4; ++i)
      af[i] = *(const short8*)&Ac[(wr + i * 16 + lrow) * 32 + lk8];
#pragma unroll
    for (int i = 0; i < 4; ++i)
      bfr[i] = *(const short8*)&Bc[(wc + i * 16 + lrow) * 32 + lk8];
#pragma unroll
    for (int mi = 0; mi < 4; ++mi)
#pragma unroll
      for (int ni = 0; ni < 4; ++ni)
        acc[mi][ni] = mfma_bf16(af[mi], bfr[ni], acc[mi][ni]);

    ++cur; if (cur == 3) cur = 0;
  }

  // fused epilogue: wave's 64 cols = one head; sector is BLOCK-uniform
  int colbase = n0 + wc;
  int sector = n0 >> 10;               // 0=q, 1=k, 2=v
  int h = (colbase & 1023) >> 6;
  if (sector < 2) {
    ushort* dst = (sector == 0) ? qb : kb;
    const float SCq = (sector == 0) ? 0.125f * 1.44269504f : 1.0f;
#pragma unroll
    for (int mi = 0; mi < 4; ++mi)
#pragma unroll
      for (int j = 0; j < 4; ++j) {
        int row = m0 + wr + mi * 16 + g * 4 + j;
        int b = row >> 11, s = row & 2047;
        size_t o = ((size_t)(b * NH_ + h) * S_ + s) * HD_;
        float c0 = ct[s * 32 + lrow],      s0 = st[s * 32 + lrow];
        float c1 = ct[s * 32 + 16 + lrow], s1 = st[s * 32 + 16 + lrow];
        float x1a = acc[mi][0][j], x2a = acc[mi][2][j];   // d = lrow, +32
        float x1b = acc[mi][1][j], x2b = acc[mi][3][j];   // d = 16+lrow, +48
        dst[o + lrow]      = f2bf((x1a * c0 - x2a * s0) * SCq);
        dst[o + lrow + 32] = f2bf((x2a * c0 + x1a * s0) * SCq);
        dst[o + lrow + 16] = f2bf((x1b * c1 - x2b * s1) * SCq);
        dst[o + lrow + 48] = f2bf((x2b * c1 + x1b * s1) * SCq);
      }
  } else {
    // V: stage [col][s] (swizzled) in SMEM[0..32KB), then coalesced
    // 64B stores along s. Block-uniform barriers.
    __syncthreads();
#pragma unroll
    for (int mi = 0; mi < 4; ++mi) {
      int s_local = wr + mi * 16 + g * 4;
#pragma unroll
      for (int ni = 0; ni < 4; ++ni) {
        int cl = wc + ni * 16 + lrow;
        uint2 pk;
        pk.x = cvtpk(acc[mi][ni][0], acc[mi][ni][1]);
        pk.y = cvtpk(acc[mi][ni][2], acc[mi][ni][3]);
        int a = cl * 128 + (((s_local >> 3) ^ (cl & 7)) << 3) + (s_local & 7);
        *(uint2*)&SMEM[a] = pk;
      }
    }
    __syncthreads();
    int b = m0 >> 11, s_base = m0 & 2047;
#pragma unroll
    for (int cc = 0; cc < 2; ++cc) {
      int u = cc * 256 + t;            // 512 units: 128 cols x 4 s-chunks
      int cl = u >> 2;
      int sq = (u & 3) * 32;
      int hh = ((n0 + cl) & 1023) >> 6;
      int d  = cl & 63;
      size_t ob = ((size_t)(b * NH_ + hh) * HD_ + d) * S_ + s_base + sq;
#pragma unroll
      for (int i = 0; i < 4; ++i) {
        int sl = sq + i * 8;
        int a = cl * 128 + (((sl >> 3) ^ (cl & 7)) << 3);
        *(short8*)&vt[ob + i * 8] = *(const short8*)&SMEM[a];
      }
    }
  }
}

// ---------------------------------------------------------------- out GEMM
// 64x128 tiles -> 512 blocks = 2 blocks/CU TLP. BK=32, triple-buffered
// (36 KB), counted vmcnt(3) (batch = 3 loads: A 1 + B 2). C f32.
__global__ __launch_bounds__(256)
void gemm_out(const ushort* __restrict__ A, const ushort* __restrict__ Bm,
              float* __restrict__ Cout, int Ndim, int Kdim) {
  __shared__ ushort SMEM[3 * 2048 + 3 * 4096];   // A bufs 3x4KB, B bufs 3x8KB
  ushort* ABUF = SMEM;                           // [3][64*32]
  ushort* BBUF = SMEM + 3 * 2048;                // [3][128*32]
  int t = threadIdx.x;
  int w = t >> 6, l = t & 63;
  int nbx = (int)gridDim.x;                      // 8 (n tiles of 128)
  int nwg = nbx * (int)gridDim.y;                // 512
  int bid = (int)blockIdx.x + nbx * (int)blockIdx.y;
  int cpx = nwg >> 3;
  int sbid = (bid & 7) * cpx + (bid >> 3);
  int m0 = (sbid / nbx) * 64, n0 = (sbid % nbx) * 128;
  int wr = (w >> 1) * 32, wc = (w & 1) * 64;
  int lrow = l & 15, g = l >> 4, lk8 = g * 8;
  int arow = t >> 2, acol = (t & 3) * 8;   // A: 64 rows x 4 chunks; B adds +64

  f32x4 acc[2][4];
#pragma unroll
  for (int mi = 0; mi < 2; ++mi)
#pragma unroll
    for (int ni = 0; ni < 4; ++ni) acc[mi][ni] = f32x4{0.f, 0.f, 0.f, 0.f};

  int nk = Kdim >> 5;
#pragma unroll
  for (int pt = 0; pt < 2; ++pt) {
    int k0 = pt << 5;
    ushort* An = ABUF + pt * 2048;
    ushort* Bn = BBUF + pt * 4096;
    gload_lds16(&A[(size_t)(m0 + arow) * Kdim + k0 + acol], &An[t * 8]);
#pragma unroll
    for (int c = 0; c < 2; ++c)
      gload_lds16(&Bm[(size_t)(n0 + arow + c * 64) * Kdim + k0 + acol],
                  &Bn[(c * 256 + w * 64) * 8]);
  }

  int cur = 0;
  for (int ki = 0; ki < nk; ++ki) {
    if (ki < nk - 1)
      asm volatile("s_waitcnt vmcnt(3)" ::: "memory");
    else
      asm volatile("s_waitcnt vmcnt(0)" ::: "memory");
    __builtin_amdgcn_s_barrier();

    if (ki + 2 < nk) {
      int tb = cur + 2; if (tb >= 3) tb -= 3;
      int k0 = (ki + 2) << 5;
      ushort* An = ABUF + tb * 2048;
      ushort* Bn = BBUF + tb * 4096;
      gload_lds16(&A[(size_t)(m0 + arow) * Kdim + k0 + acol], &An[t * 8]);
#pragma unroll
      for (int c = 0; c < 2; ++c)
        gload_lds16(&Bm[(size_t)(n0 + arow + c * 64) * Kdim + k0 + acol],
                    &Bn[(c * 256 + w * 64) * 8]);
    }

    const ushort* Ac = ABUF + cur * 2048;
    const ushort* Bc = BBUF + cur * 4096;
    short8 af[2], bfr[4];
#pragma unroll
    for (int i = 0; i < 2; ++i)
      af[i] = *(const short8*)&Ac[(wr + i * 16 + lrow) * 32 + lk8];
#pragma unroll
    for (int i = 0; i < 4; ++i)
      bfr[i] = *(const short8*)&Bc[(wc + i * 16 + lrow) * 32 + lk8];
#pragma unroll
    for (int mi = 0; mi < 2; ++mi)
#pragma unroll
      for (int ni = 0; ni < 4; ++ni)
        acc[mi][ni] = mfma_bf16(af[mi], bfr[ni], acc[mi][ni]);

    ++cur; if (cur == 3) cur = 0;
  }

#pragma unroll
  for (int mi = 0; mi < 2; ++mi)
#pragma unroll
    for (int ni = 0; ni < 4; ++ni)
#pragma unroll
      for (int j = 0; j < 4; ++j) {
        int row = m0 + wr + mi * 16 + g * 4 + j;
        int col = n0 + wc + ni * 16 + lrow;
        Cout[(size_t)row * Ndim + col] = acc[mi][ni][j];
      }
}

// ---------------------------------------------------------------- flash attention v10
// (best measured: 45.3 µs) 64 KB LDS; Q direct-to-reg; K single-buffered
// (staged post-QK-barrier, hidden under softmax+PV); V double-buffered.
__global__ __launch_bounds__(512, 4)
void flash_attn(const ushort* __restrict__ qb, const ushort* __restrict__ kb,
                const ushort* __restrict__ vt, ushort* __restrict__ ctx) {
  __shared__ ushort Ks[128 * 64];      // [key][d] swizzled, single buffer
  __shared__ ushort Vs[2][64 * 128];   // [d][key] swizzled, double buffer
  __shared__ ushort Ps[128 * 64];      // P (swizzled), wave-private rows
  int bh = blockIdx.y;
  int qt = (blockIdx.y & 16) ? (int)blockIdx.x : (15 - (int)blockIdx.x);
  int b = bh >> 4, h = bh & 15;
  int t = threadIdx.x, w = t >> 6, l = t & 63;
  int lrow = l & 15, g = l >> 4;
  int wrow = w * 16;
  const ushort* Q = qb + (size_t)bh * S_ * HD_;
  const ushort* K = kb + (size_t)bh * S_ * HD_;
  const ushort* V = vt + (size_t)bh * HD_ * S_;   // [64][2048]

  short8 ones;
#pragma unroll
  for (int i = 0; i < 8; ++i) ones[i] = (short)0x3F80;   // bf16 1.0

  // prologue: K/V tile 0 -> LDS; Q -> registers
#pragma unroll
  for (int cc = 0; cc < 2; ++cc) {
    int slot = cc * 512 + t;
    int r = slot >> 3, c = slot & 7;
    int cs = (c ^ (r & 7)) << 3;
    gload_lds16(&K[(size_t)r * 64 + cs], &Ks[slot * 8]);
  }
#pragma unroll
  for (int cc = 0; cc < 2; ++cc) {
    int slot = cc * 512 + t;
    int r = slot >> 4, c = slot & 15;
    int cs = (c ^ (r & 7)) << 3;
    gload_lds16(&V[(size_t)r * S_ + cs], &Vs[0][slot * 8]);
  }
  short8 aq[2];
  {
    int qrow = qt * 128 + wrow + lrow;
#pragma unroll
    for (int ks = 0; ks < 2; ++ks)
      aq[ks] = *(const short8*)&Q[(size_t)qrow * 64 + ks * 32 + g * 8];
  }
  __syncthreads();

  float m_ = -1e30f, ls_ = 0.f;
  f32x4 O[4];
#pragma unroll
  for (int nf = 0; nf < 4; ++nf) O[nf] = f32x4{0.f, 0.f, 0.f, 0.f};

  int nkt = qt + 1;
  for (int kt = 0; kt < nkt; ++kt) {
    const ushort* Vc = Vs[kt & 1];

    // S^T = K Q^T : lane q = wrow+lrow; key = nf*16 + g*4 + j
    f32x4 sc[8];
#pragma unroll
    for (int nf = 0; nf < 8; ++nf) sc[nf] = f32x4{0.f, 0.f, 0.f, 0.f};
    __builtin_amdgcn_s_setprio(1);
#pragma unroll
    for (int ks = 0; ks < 2; ++ks)
#pragma unroll
      for (int nf = 0; nf < 8; ++nf) {
        short8 bk = *(const short8*)&Ks[swzK(nf * 16 + lrow, ks * 4 + g)];
        sc[nf] = mfma_bf16(bk, aq[ks], sc[nf]);
      }
    __builtin_amdgcn_s_setprio(0);

    __syncthreads();   // all waves done reading Ks; nothing else in flight

    // stage K/V for kt+1 (async; lands during softmax+PV below)
    if (kt + 1 < nkt) {
      int nb = (kt + 1) & 1;
#pragma unroll
      for (int cc = 0; cc < 2; ++cc) {
        int slot = cc * 512 + t;
        int r = slot >> 3, c = slot & 7;
        int cs = (c ^ (r & 7)) << 3;
        gload_lds16(&K[(size_t)((kt + 1) * 128 + r) * 64 + cs], &Ks[slot * 8]);
      }
#pragma unroll
      for (int cc = 0; cc < 2; ++cc) {
        int slot = cc * 512 + t;
        int r = slot >> 4, c = slot & 15;
        int cs = (c ^ (r & 7)) << 3;
        gload_lds16(&V[(size_t)r * S_ + (kt + 1) * 128 + cs], &Vs[nb][slot * 8]);
      }
    }

    int qbase = qt * 128 + wrow;
    if (kt * 128 + 127 > qbase) {   // wave-uniform; only the diagonal tile
      int qi = qbase + lrow;
#pragma unroll
      for (int nf = 0; nf < 8; ++nf) {
        int kbase = kt * 128 + nf * 16 + g * 4;
#pragma unroll
        for (int j = 0; j < 4; ++j)
          if (kbase + j > qi) sc[nf][j] = -1e30f;
      }
    }

    // row max: pairwise tree + 2 shuffles
    f32x4 v4 = sc[0];
#pragma unroll
    for (int nf = 1; nf < 8; ++nf)
#pragma unroll
      for (int j = 0; j < 4; ++j) v4[j] = fmaxf(v4[j], sc[nf][j]);
    float mx = redmax64(fmaxf(fmaxf(v4[0], v4[1]), fmaxf(v4[2], v4[3])));

    // defer-max (T13)
    bool nor = __all(mx <= m_ + 8.f);
    if (!nor) {
      float mnew = fmaxf(m_, mx);
      float al = exp2f(m_ - mnew);
      m_ = mnew;
      ls_ *= al;
#pragma unroll
      for (int nf = 0; nf < 4; ++nf)
#pragma unroll
        for (int j = 0; j < 4; ++j) O[nf][j] *= al;
    }

    // exp2 (row sum comes from the ones-MFMA below)
#pragma unroll
    for (int nf = 0; nf < 8; ++nf)
#pragma unroll
      for (int j = 0; j < 4; ++j) sc[nf][j] = exp2f(sc[nf][j] - m_);

    // PV in two 64-key halves through the wave-private P rows;
    // sacc accumulates the bf16-P row sum via mfma(ones, ap).
    f32x4 sacc = f32x4{0.f, 0.f, 0.f, 0.f};
#pragma unroll
    for (int half = 0; half < 2; ++half) {
      int prow = wrow + lrow;
#pragma unroll
      for (int nf2 = 0; nf2 < 4; ++nf2) {
        int nf = half * 4 + nf2;
        uint2 pk;
        pk.x = cvtpk(sc[nf][0], sc[nf][1]);
        pk.y = cvtpk(sc[nf][2], sc[nf][3]);
        *(uint2*)&Ps[swzK(prow, nf2 * 2 + (g >> 1)) + (g & 1) * 4] = pk;
      }
      __builtin_amdgcn_s_setprio(1);
#pragma unroll
      for (int ks2 = 0; ks2 < 2; ++ks2) {
        short8 ap = *(const short8*)&Ps[swzK(wrow + lrow, ks2 * 4 + g)];
        sacc = mfma_bf16(ones, ap, sacc);   // row sum, replicated in all regs
#pragma unroll
        for (int nf = 0; nf < 4; ++nf) {
          short8 bv = *(const short8*)&Vc[swzV(nf * 16 + lrow, half * 8 + ks2 * 4 + g)];
          O[nf] = mfma_bf16(bv, ap, O[nf]);
        }
      }
      __builtin_amdgcn_s_setprio(0);
    }
    ls_ += sacc[0];

    __syncthreads();   // staging drained; K/V ready for kt+1
  }

  // epilogue: lane q = wrow+lrow, d = nf*16 + g*4 + j
  float inv = 1.f / ls_;
  int srow = qt * 128 + wrow + lrow;
#pragma unroll
  for (int nf = 0; nf < 4; ++nf) {
    uint2 pk;
    pk.x = cvtpk(O[nf][0] * inv, O[nf][1] * inv);
    pk.y = cvtpk(O[nf][2] * inv, O[nf][3] * inv);
    *(uint2*)&ctx[((size_t)b * S_ + srow) * H_ + h * 64 + nf * 16 + g * 4] = pk;
  }
}

// ---------------------------------------------------------------- launch
extern "C" void kernel_launch(void* const* d_in, const int* in_sizes, int n_in,
                              void* d_out, int out_size, void* d_ws, size_t ws_size,
                              hipStream_t stream) {
  const float* x  = (const float*)d_in[0];
  const float* Wq = (const float*)d_in[1];
  const float* Wk = (const float*)d_in[2];
  const float* Wv = (const float*)d_in[3];
  const float* Wo = (const float*)d_in[4];

  char* ws = (char*)d_ws;
  size_t off = 0;
  ushort* xb   = (ushort*)(ws + off); off += (size_t)M_ * H_ * 2;
  ushort* Wqkv = (ushort*)(ws + off); off += (size_t)3 * H_ * H_ * 2;
  ushort* Wob  = (ushort*)(ws + off); off += (size_t)H_ * H_ * 2;
  float*  ct   = (float*)(ws + off);  off += (size_t)S_ * 32 * 4;
  float*  st   = (float*)(ws + off);  off += (size_t)S_ * 32 * 4;
  ushort* qb   = (ushort*)(ws + off); off += (size_t)M_ * H_ * 2;
  ushort* kb   = (ushort*)(ws + off); off += (size_t)M_ * H_ * 2;
  ushort* vtb  = (ushort*)(ws + off); off += (size_t)M_ * H_ * 2;
  ushort* ctx  = (ushort*)(ws + off); off += (size_t)M_ * H_ * 2;

  prep<<<8448, 256, 0, stream>>>(x, Wq, Wk, Wv, Wo, xb, Wqkv, Wob, ct, st);

  gemm_qkv<<<dim3(3 * H_ / 128, M_ / 128), 256, 0, stream>>>(
      xb, Wqkv, H_, ct, st, qb, kb, vtb);
  flash_attn<<<dim3(S_ / 128, B_ * NH_), 512, 0, stream>>>(qb, kb, vtb, ctx);
  gemm_out<<<dim3(H_ / 128, M_ / 64), 256, 0, stream>>>(
      ctx, Wob, (float*)d_out, H_, H_);
}